// Round 2
// baseline (650.499 us; speedup 1.0000x reference)
//
#include <hip/hip_runtime.h>

// Problem constants
#define D_MODEL 256
#define ARITY   32
#define MAXDEP  15
#define VOCABN  1027
#define BATCH   8192
#define KTOT    8192      // 32 children * 256
#define KQ      2048      // K quarter
#define BK      64
#define NSTEP   32        // KQ / BK
#define LN_EPS  1e-5f

// ---- workspace layout (float offsets) ----
// total bytes needed = 39,324,672 (~37.5 MiB)
#define WS_CIDXP 0         // 32*256: per-child partial of (idx_emb[a]@W_ie_a) + b
#define WS_TOP   8192      // 1027*256: token_emb @ W_op
#define WS_TDEP  271104    // 32*15*256: depth tables
#define WS_PART  393984    // 4*8192*256: GEMM K-quarter partials
#define WS_WT    8782592   // ushort bf16 Wt[256][8192] (ce weights, transposed)

typedef __attribute__((ext_vector_type(4))) float f32x4;
typedef __attribute__((ext_vector_type(8))) short bf16x8;

__device__ __forceinline__ unsigned int f2bf(float f) {
  unsigned int u = __builtin_bit_cast(unsigned int, f);
  return (u + 0x7fffu + ((u >> 16) & 1u)) >> 16;  // RNE, low 16 bits valid
}

// =====================================================================
// K0: build tables (T_op, T_dep, c_idx partials) + transpose ce-weights
// to bf16 Wt[n][k].  W row blocks: e_op rows [0,256); child a: ce rows
// 256+768a, de rows 512+768a, ie rows 768+768a (each 256 rows).
// =====================================================================
__global__ __launch_bounds__(256) void build_tables(
    const float* __restrict__ te, const float* __restrict__ de,
    const float* __restrict__ ie, const float* __restrict__ W,
    const float* __restrict__ bvec, float* __restrict__ ws) {
  __shared__ float sh[4352];
  int bid = blockIdx.x, tid = threadIdx.x;

  if (bid < 257) {  // ---- T_op: 4 vocab rows per WG ----
    int v0 = bid * 4;
    int cnt = VOCABN - v0; if (cnt > 4) cnt = 4;
    for (int j = 0; j < cnt; ++j) sh[j * 256 + tid] = te[(v0 + j) * 256 + tid];
    for (int j = cnt; j < 4; ++j) sh[j * 256 + tid] = 0.f;
    __syncthreads();
    float a0 = 0.f, a1 = 0.f, a2 = 0.f, a3 = 0.f;
#pragma unroll 8
    for (int k = 0; k < 256; ++k) {
      float wv = W[k * 256 + tid];
      a0 += sh[k] * wv;
      a1 += sh[256 + k] * wv;
      a2 += sh[512 + k] * wv;
      a3 += sh[768 + k] * wv;
    }
    float a4[4] = {a0, a1, a2, a3};
    for (int j = 0; j < cnt; ++j) ws[WS_TOP + (v0 + j) * 256 + tid] = a4[j];

  } else if (bid < 289) {  // ---- T_dep: all 15 depths for one child a ----
    int a = bid - 257;
    for (int d = 0; d < MAXDEP; ++d) sh[d * 256 + tid] = de[d * 256 + tid];
    __syncthreads();
    float acc[MAXDEP];
#pragma unroll
    for (int d = 0; d < MAXDEP; ++d) acc[d] = 0.f;
    const float* Wb = W + ((size_t)(512 + 768 * a)) * 256;
#pragma unroll 2
    for (int k = 0; k < 256; ++k) {
      float wv = Wb[(size_t)k * 256 + tid];
#pragma unroll
      for (int d = 0; d < MAXDEP; ++d) acc[d] += sh[d * 256 + k] * wv;
    }
    for (int d = 0; d < MAXDEP; ++d)
      ws[WS_TDEP + (a * MAXDEP + d) * 256 + tid] = acc[d];

  } else if (bid < 321) {  // ---- c_idx partial for one child a (+bias at a==0) ----
    int a = bid - 289;
    sh[tid] = ie[a * 256 + tid];
    __syncthreads();
    float acc = (a == 0) ? bvec[tid] : 0.f;
    const float* Wb = W + ((size_t)(768 + 768 * a)) * 256;
#pragma unroll 8
    for (int k = 0; k < 256; ++k) acc += sh[k] * Wb[(size_t)k * 256 + tid];
    ws[WS_CIDXP + a * 256 + tid] = acc;

  } else {  // ---- Wt transpose tiles: 64k x 64n per WG ----
    int j = bid - 321;            // 0..511
    int kt = j >> 2, nt = j & 3;
    int kr = tid >> 2, q = tid & 3;
    int kk = kt * 64 + kr;
    int a = kk >> 8, kp = kk & 255;
    const float* src = W + ((size_t)(256 + 768 * a + kp)) * 256 + nt * 64 + q * 16;
    float4 v0 = *(const float4*)(src);
    float4 v1 = *(const float4*)(src + 4);
    float4 v2 = *(const float4*)(src + 8);
    float4 v3 = *(const float4*)(src + 12);
    float* row = sh + kr * 68 + q * 16;   // pad 68 keeps float4 alignment
    *(float4*)(row) = v0; *(float4*)(row + 4) = v1;
    *(float4*)(row + 8) = v2; *(float4*)(row + 12) = v3;
    __syncthreads();
    int nl = tid >> 2, c = tid & 3;
#define PK(i) (f2bf(sh[(c * 16 + 2 * (i)) * 68 + nl]) | (f2bf(sh[(c * 16 + 2 * (i) + 1) * 68 + nl]) << 16))
    uint4 u0 = make_uint4(PK(0), PK(1), PK(2), PK(3));
    uint4 u1 = make_uint4(PK(4), PK(5), PK(6), PK(7));
#undef PK
    unsigned short* Wt = (unsigned short*)(ws + WS_WT);
    unsigned short* dst = Wt + (size_t)(nt * 64 + nl) * KTOT + kt * 64 + c * 16;
    *(uint4*)(dst) = u0;
    *(uint4*)(dst + 8) = u1;
  }
}

// =====================================================================
// K1: bf16 MFMA GEMM over the child_embs blocks.
// grid = 128 M-tiles x 4 K-quarters; block = 512 (8 waves as 2m x 4n),
// BM=64, BN=256, BK=64.  Each wave: 32m x 64n, acc[2][4].
// LDS tiles XOR-swizzled (chunk ^= row&7) on write and read.
// =====================================================================
__global__ __launch_bounds__(512, 4) void gemm_ce(
    const float* __restrict__ ce, float* __restrict__ ws) {
  const unsigned short* Wt = (const unsigned short*)(ws + WS_WT);
  float* part = ws + WS_PART;

  __shared__ uint4 Al[64 * 8];    // [row][chunk]  8 KiB (64 x 64 bf16)
  __shared__ uint4 Wl[256 * 8];   // [n][chunk]   32 KiB (64k x 256n)

  int mt = blockIdx.x >> 2, kq = blockIdx.x & 3;
  int m0 = mt * 64;
  int tid = threadIdx.x;
  int lane = tid & 63, wid = tid >> 6;
  int wm = wid & 1, wn = wid >> 1;       // wave's m-half / n-quarter
  int arow = tid >> 3, acol = tid & 7;   // A staging: row 0..63, 16B-chunk
  int wrow = tid >> 3, wcol = tid & 7;   // W staging: n base 0..63, chunk

  f32x4 acc[2][4] = {};

  float4 ra0, ra1;
  uint4 rw[4];

#define LOAD_A(KKE) { int kk_ = (KKE); int a_ = kk_ >> 8, kp_ = kk_ & 255;            \
    const float* asrc = ce + ((size_t)a_ * BATCH + m0 + arow) * 256 + kp_ + acol * 8; \
    ra0 = *(const float4*)asrc; ra1 = *(const float4*)(asrc + 4); }
#define LOAD_W(KKE) { int kk_ = (KKE);                                                \
    const unsigned short* wsrc = Wt + kk_ + wcol * 8;                                 \
    _Pragma("unroll")                                                                 \
    for (int i = 0; i < 4; ++i)                                                       \
      rw[i] = *(const uint4*)(wsrc + (size_t)(i * 64 + wrow) * KTOT); }

  LOAD_A(kq * KQ);
  LOAD_W(kq * KQ);

#pragma unroll 1
  for (int t = 0; t < NSTEP; ++t) {
    __syncthreads();   // previous tile fully consumed
    // ---- stage A (f32 -> bf16) swizzled ----
    unsigned int p0 = f2bf(ra0.x) | (f2bf(ra0.y) << 16);
    unsigned int p1 = f2bf(ra0.z) | (f2bf(ra0.w) << 16);
    unsigned int p2 = f2bf(ra1.x) | (f2bf(ra1.y) << 16);
    unsigned int p3 = f2bf(ra1.z) | (f2bf(ra1.w) << 16);
    Al[arow * 8 + (acol ^ (arow & 7))] = make_uint4(p0, p1, p2, p3);
    // ---- stage W swizzled ----
#pragma unroll
    for (int i = 0; i < 4; ++i) {
      int n = i * 64 + wrow;
      Wl[n * 8 + (wcol ^ (n & 7))] = rw[i];
    }
    // ---- prefetch next K-step while this one computes ----
    if (t + 1 < NSTEP) { LOAD_A(kq * KQ + (t + 1) * BK); LOAD_W(kq * KQ + (t + 1) * BK); }
    __syncthreads();   // tile ready
    // ---- MFMA ----
    int r0 = lane & 15, g = lane >> 4;
#pragma unroll
    for (int kg = 0; kg < 2; ++kg) {
      int chunk = kg * 4 + g;
      bf16x8 af[2], bfr[4];
#pragma unroll
      for (int m = 0; m < 2; ++m)
        af[m] = __builtin_bit_cast(bf16x8, Al[(wm * 32 + m * 16 + r0) * 8 + (chunk ^ (r0 & 7))]);
#pragma unroll
      for (int n = 0; n < 4; ++n) {
        int col = wn * 64 + n * 16 + r0;
        bfr[n] = __builtin_bit_cast(bf16x8, Wl[col * 8 + (chunk ^ (r0 & 7))]);
      }
#pragma unroll
      for (int m = 0; m < 2; ++m)
#pragma unroll
        for (int n = 0; n < 4; ++n)
          acc[m][n] = __builtin_amdgcn_mfma_f32_16x16x32_bf16(af[m], bfr[n], acc[m][n], 0, 0, 0);
    }
  }
#undef LOAD_A
#undef LOAD_W

  // ---- store partials (C/D layout: col=lane&15, row=(lane>>4)*4+reg) ----
  float* p = part + ((size_t)kq * BATCH + m0) * 256;
  int r0 = lane & 15, g = lane >> 4;
#pragma unroll
  for (int m = 0; m < 2; ++m)
#pragma unroll
    for (int n = 0; n < 4; ++n)
#pragma unroll
      for (int r = 0; r < 4; ++r)
        p[(wm * 32 + m * 16 + g * 4 + r) * 256 + wn * 64 + n * 16 + r0] = acc[m][n][r];
}

// =====================================================================
// K2: partial sum + table gathers + bias/idx const + ReLU + LayerNorm
// grid = 256 WGs x 32 batch rows each.
// =====================================================================
__global__ __launch_bounds__(256) void epilogue(
    const int* __restrict__ nid, const int* __restrict__ cdep,
    const float* __restrict__ ws, const float* __restrict__ lng,
    const float* __restrict__ lnb, float* __restrict__ out) {
  __shared__ float h[32][256];
  __shared__ int cdl[32][32];
  __shared__ int nidl[32];
  int m0 = blockIdx.x * 32, tid = threadIdx.x;
#pragma unroll
  for (int i = 0; i < 4; ++i) {
    int idx = i * 256 + tid;
    int a = idx >> 5, r = idx & 31;
    cdl[r][a] = cdep[a * BATCH + m0 + r];
  }
  if (tid < 32) nidl[tid] = nid[m0 + tid];
  __syncthreads();

  int col = tid;
  float ci = 0.f;
#pragma unroll 8
  for (int a = 0; a < ARITY; ++a) ci += ws[WS_CIDXP + a * 256 + col];

  const float* p0 = ws + WS_PART + (size_t)m0 * 256;
  const float* Top = ws + WS_TOP;
  const float* Td  = ws + WS_TDEP;

  for (int r = 0; r < 32; ++r) {
    float v = ci + Top[(size_t)nidl[r] * 256 + col];
#pragma unroll
    for (int q = 0; q < 4; ++q)
      v += p0[(size_t)q * BATCH * 256 + r * 256 + col];
#pragma unroll
    for (int a = 0; a < ARITY; ++a)
      v += Td[(size_t)(a * MAXDEP + cdl[r][a]) * 256 + col];
    h[r][col] = fmaxf(v, 0.f);
  }
  __syncthreads();

  int lane = tid & 63, w = tid >> 6;
  for (int rr = 0; rr < 8; ++rr) {
    int r = w * 8 + rr;
    float x0 = h[r][lane],       x1 = h[r][64 + lane];
    float x2 = h[r][128 + lane], x3 = h[r][192 + lane];
    float s = x0 + x1 + x2 + x3;
    float q = x0 * x0 + x1 * x1 + x2 * x2 + x3 * x3;
#pragma unroll
    for (int off = 32; off >= 1; off >>= 1) {
      s += __shfl_xor(s, off);
      q += __shfl_xor(q, off);
    }
    float mu = s * (1.f / 256.f);
    float var = q * (1.f / 256.f) - mu * mu;
    float rs = rsqrtf(var + LN_EPS);
    float* o = out + (size_t)(m0 + r) * 256;
    o[lane]       = (x0 - mu) * rs * lng[lane]       + lnb[lane];
    o[64 + lane]  = (x1 - mu) * rs * lng[64 + lane]  + lnb[64 + lane];
    o[128 + lane] = (x2 - mu) * rs * lng[128 + lane] + lnb[128 + lane];
    o[192 + lane] = (x3 - mu) * rs * lng[192 + lane] + lnb[192 + lane];
  }
}

extern "C" void kernel_launch(void* const* d_in, const int* in_sizes, int n_in,
                              void* d_out, int out_size, void* d_ws, size_t ws_size,
                              hipStream_t stream) {
  const int*   nid  = (const int*)d_in[0];
  const float* ce   = (const float*)d_in[1];   // child_embs [32][8192][256]
  const int*   cdep = (const int*)d_in[2];     // child_depths [32][8192]
  const float* te   = (const float*)d_in[3];   // token_emb [1027][256]
  const float* de   = (const float*)d_in[4];   // depth_emb [15][256]
  const float* ie   = (const float*)d_in[5];   // idx_emb [32][256]
  const float* W    = (const float*)d_in[6];   // [24832][256]
  const float* bv   = (const float*)d_in[7];
  const float* lng  = (const float*)d_in[8];
  const float* lnb  = (const float*)d_in[9];
  float* out = (float*)d_out;
  float* ws  = (float*)d_ws;   // needs ~37.5 MiB

  build_tables<<<dim3(833), dim3(256), 0, stream>>>(te, de, ie, W, bv, ws);
  gemm_ce<<<dim3(512), dim3(512), 0, stream>>>(ce, ws);
  epilogue<<<dim3(256), dim3(256), 0, stream>>>(nid, cdep, ws, lng, lnb, out);
}